// Round 1
// baseline (460.273 us; speedup 1.0000x reference)
//
#include <hip/hip_runtime.h>

#define BB 8
#define NN 20000
#define CC 20
#define LL 200
#define MAX_DET 300
#define SCORE_THR 0.05f
#define NEGV -1e9f
#define NBINS 1024
#define CAP 1024
#define TOPM 512
#define TARGET1 512
#define TARGET2 300

#define OFF_SCORES (BB * MAX_DET * 4)              // 9600
#define OFF_LABELS (OFF_SCORES + BB * MAX_DET)     // 12000
#define OFF_LSC    (OFF_LABELS + BB * MAX_DET)     // 14400
#define OFF_LLB    (OFF_LSC + BB * MAX_DET)        // 16800

// ---------------------------------------------------------------------------
// K1: per-(batch,class) NMS. One block per (b,c). 160 blocks x 256 threads.
// ---------------------------------------------------------------------------
__global__ __launch_bounds__(256) void k1_nms(const float* __restrict__ boxes,
                                              const float* __restrict__ cls,
                                              float* __restrict__ cand_score,
                                              int* __restrict__ cand_anchor) {
    const int bc = blockIdx.x;
    const int b = bc / CC;
    const int c = bc % CC;
    const float* sc = cls + (size_t)b * NN * CC + c;
    const float* bx = boxes + (size_t)b * NN * 4;

    __shared__ unsigned hist[NBINS];
    __shared__ unsigned long long keys[CAP];
    __shared__ float4 cbox[TOPM];
    __shared__ float carea[TOPM];
    __shared__ unsigned long long mask[TOPM * 8];
    __shared__ int keptIdx[MAX_DET];
    __shared__ unsigned gsum[32];
    __shared__ int sh_cutoff, sh_cnt, sh_k;

    const int tid = threadIdx.x;
    const int wave = tid >> 6, lane = tid & 63;

    for (int i = tid; i < NBINS; i += 256) hist[i] = 0u;
    __syncthreads();

    // histogram of scores above threshold
    for (int i = tid; i < NN; i += 256) {
        float s = sc[(size_t)i * CC];
        if (s > SCORE_THR) {
            int bin = (int)(s * 1024.0f);
            bin = min(max(bin, 0), NBINS - 1);
            atomicAdd(&hist[bin], 1u);
        }
    }
    __syncthreads();
    if (tid < 32) {
        unsigned sum = 0;
        for (int i = 0; i < 32; ++i) sum += hist[tid * 32 + i];
        gsum[tid] = sum;
    }
    __syncthreads();
    if (tid == 0) {
        unsigned acc = 0;
        int cutoff = 0;
        int g = 31;
        for (; g >= 0; --g) {
            if (acc + gsum[g] >= (unsigned)TARGET1) break;
            acc += gsum[g];
        }
        if (g >= 0) {
            int bin = g * 32 + 31;
            for (; bin > g * 32; --bin) {
                acc += hist[bin];
                if (acc >= (unsigned)TARGET1) break;
            }
            if (bin == g * 32) { /* lands on group base */ }
            cutoff = bin;
        }
        sh_cutoff = cutoff;
        sh_cnt = 0;
    }
    __syncthreads();
    const int cutoff = sh_cutoff;

    // compact candidates at/above cutoff bin
    for (int i = tid; i < NN; i += 256) {
        float s = sc[(size_t)i * CC];
        if (s > SCORE_THR) {
            int bin = (int)(s * 1024.0f);
            bin = min(max(bin, 0), NBINS - 1);
            if (bin >= cutoff) {
                int p = atomicAdd(&sh_cnt, 1);
                if (p < CAP) {
                    keys[p] = ((unsigned long long)__float_as_uint(s) << 32) |
                              (unsigned long long)(0xFFFFFFFFu - (unsigned)i);
                }
            }
        }
    }
    __syncthreads();
    const int cnt = min(sh_cnt, CAP);
    for (int i = tid; i < CAP; i += 256)
        if (i >= cnt) keys[i] = 0ull;
    __syncthreads();

    // bitonic sort descending, n = CAP = 1024
    for (unsigned k = 2; k <= CAP; k <<= 1) {
        for (unsigned j = k >> 1; j > 0; j >>= 1) {
            for (unsigned t = tid; t < CAP; t += 256) {
                unsigned p = t ^ j;
                if (p > t) {
                    unsigned long long a = keys[t], d = keys[p];
                    bool descdir = ((t & k) == 0);
                    if (descdir ? (a < d) : (a > d)) { keys[t] = d; keys[p] = a; }
                }
            }
            __syncthreads();
        }
    }

    const int M = min(cnt, TOPM);
    // stage candidate boxes + areas
    for (int i = tid; i < TOPM; i += 256) {
        if (i < M) {
            unsigned anchor = 0xFFFFFFFFu - (unsigned)(keys[i] & 0xFFFFFFFFull);
            float4 v = *(const float4*)(bx + (size_t)anchor * 4);
            cbox[i] = v;
            carea[i] = (v.z - v.x) * (v.w - v.y);
        } else {
            cbox[i] = make_float4(0.f, 0.f, 0.f, 0.f);
            carea[i] = 0.f;
        }
    }
    for (int i = tid; i < TOPM * 8; i += 256) mask[i] = 0ull;
    __syncthreads();

    // suppression bitmask: 8x8 tiles of 64x64, upper triangle only
    for (int tile = wave; tile < 36; tile += 4) {
        int ti = 0, rem = tile;
        while (rem >= (8 - ti)) { rem -= (8 - ti); ti++; }
        int tj = ti + rem;
        int i = ti * 64 + lane;
        float4 bi = cbox[i];
        float ai = carea[i];
        unsigned long long word = 0ull;
#pragma unroll 8
        for (int s = 0; s < 64; ++s) {
            int j = tj * 64 + s;
            float4 bj = cbox[j];   // uniform address -> LDS broadcast
            float aj = carea[j];
            float x1 = fmaxf(bi.x, bj.x);
            float y1 = fmaxf(bi.y, bj.y);
            float x2 = fminf(bi.z, bj.z);
            float y2 = fminf(bi.w, bj.w);
            float iw = fmaxf(x2 - x1, 0.0f);
            float ih = fmaxf(y2 - y1, 0.0f);
            float inter = iw * ih;
            float denom = ai + aj - inter + 1e-8f;
            float d2 = inter - 0.5f * denom;
            bool sup;
            if (fabsf(d2) <= 1e-4f * denom) {
                // borderline: match reference's IEEE division exactly
                sup = (inter / denom > 0.5f);
            } else {
                sup = (d2 > 0.0f);
            }
            sup = sup && (j > i) && (j < M) && (i < M);
            word |= ((unsigned long long)(sup ? 1u : 0u)) << s;
        }
        mask[i * 8 + tj] = word;
    }
    __syncthreads();

    // sequential greedy resolve on wave 0 (lane l<8 holds suppression word l)
    if (wave == 0) {
        unsigned long long suppw = 0ull;
        int k = 0;
        for (int i = 0; i < M && k < MAX_DET; ++i) {
            unsigned long long cur = __shfl(suppw, i >> 6);
            if (!((cur >> (i & 63)) & 1ull)) {
                if (lane == 0) keptIdx[k] = i;
                if (lane < 8) suppw |= mask[i * 8 + lane];
                k++;
            }
        }
        if (lane == 0) sh_k = k;
    }
    __syncthreads();

    const int kk = sh_k;
    const size_t obase = (size_t)bc * MAX_DET;
    for (int t = tid; t < MAX_DET; t += 256) {
        if (t < kk) {
            int p = keptIdx[t];
            unsigned long long key = keys[p];
            cand_score[obase + t] = __uint_as_float((unsigned)(key >> 32));
            cand_anchor[obase + t] = (int)(0xFFFFFFFFu - (unsigned)(key & 0xFFFFFFFFull));
        } else {
            cand_score[obase + t] = NEGV;
            cand_anchor[obase + t] = 0;
        }
    }
}

// ---------------------------------------------------------------------------
// K2: per-batch global top-300 over 6000 per-class survivors. 8 blocks.
// ---------------------------------------------------------------------------
__global__ __launch_bounds__(256) void k2_topk(const float* __restrict__ boxes,
                                               const float* __restrict__ cand_score,
                                               const int* __restrict__ cand_anchor,
                                               float* __restrict__ out,
                                               int* __restrict__ sel_anchor) {
    const int b = blockIdx.x;
    const int NC = CC * MAX_DET;  // 6000
    const float* cs = cand_score + (size_t)b * NC;

    __shared__ unsigned hist[NBINS];
    __shared__ unsigned long long keys[CAP];
    __shared__ unsigned gsum[32];
    __shared__ int sh_cutoff, sh_cnt;

    const int tid = threadIdx.x;
    for (int i = tid; i < NBINS; i += 256) hist[i] = 0u;
    __syncthreads();
    for (int i = tid; i < NC; i += 256) {
        float s = cs[i];
        if (s > 0.0f) {
            int bin = min(max((int)(s * 1024.0f), 0), NBINS - 1);
            atomicAdd(&hist[bin], 1u);
        }
    }
    __syncthreads();
    if (tid < 32) {
        unsigned sum = 0;
        for (int i = 0; i < 32; ++i) sum += hist[tid * 32 + i];
        gsum[tid] = sum;
    }
    __syncthreads();
    if (tid == 0) {
        unsigned acc = 0;
        int cutoff = 0;
        int g = 31;
        for (; g >= 0; --g) {
            if (acc + gsum[g] >= (unsigned)TARGET2) break;
            acc += gsum[g];
        }
        if (g >= 0) {
            int bin = g * 32 + 31;
            for (; bin > g * 32; --bin) {
                acc += hist[bin];
                if (acc >= (unsigned)TARGET2) break;
            }
            cutoff = bin;
        }
        sh_cutoff = cutoff;
        sh_cnt = 0;
    }
    __syncthreads();
    const int cutoff = sh_cutoff;
    for (int i = tid; i < NC; i += 256) {
        float s = cs[i];
        if (s > 0.0f) {
            int bin = min(max((int)(s * 1024.0f), 0), NBINS - 1);
            if (bin >= cutoff) {
                int p = atomicAdd(&sh_cnt, 1);
                if (p < CAP) {
                    keys[p] = ((unsigned long long)__float_as_uint(s) << 32) |
                              (unsigned long long)(0xFFFFFFFFu - (unsigned)i);
                }
            }
        }
    }
    __syncthreads();
    const int cnt = min(sh_cnt, CAP);
    for (int i = tid; i < CAP; i += 256)
        if (i >= cnt) keys[i] = 0ull;
    __syncthreads();
    for (unsigned k = 2; k <= CAP; k <<= 1) {
        for (unsigned j = k >> 1; j > 0; j >>= 1) {
            for (unsigned t = tid; t < CAP; t += 256) {
                unsigned p = t ^ j;
                if (p > t) {
                    unsigned long long a = keys[t], d = keys[p];
                    bool descdir = ((t & k) == 0);
                    if (descdir ? (a < d) : (a > d)) { keys[t] = d; keys[p] = a; }
                }
            }
            __syncthreads();
        }
    }

    const int M2 = min(cnt, MAX_DET);
    for (int t = tid; t < MAX_DET; t += 256) {
        size_t orow = (size_t)b * MAX_DET + t;
        if (t < M2) {
            unsigned long long key = keys[t];
            float score = __uint_as_float((unsigned)(key >> 32));
            int flat = (int)(0xFFFFFFFFu - (unsigned)(key & 0xFFFFFFFFull));
            int cls_id = flat / MAX_DET;
            int anchor = cand_anchor[(size_t)b * NC + flat];
            const float* bb = boxes + ((size_t)b * NN + anchor) * 4;
            out[orow * 4 + 0] = bb[0];
            out[orow * 4 + 1] = bb[1];
            out[orow * 4 + 2] = bb[2];
            out[orow * 4 + 3] = bb[3];
            out[OFF_SCORES + orow] = score;
            out[OFF_LABELS + orow] = (float)cls_id;
            sel_anchor[orow] = anchor;
        } else {
            out[orow * 4 + 0] = -1.0f;
            out[orow * 4 + 1] = -1.0f;
            out[orow * 4 + 2] = -1.0f;
            out[orow * 4 + 3] = -1.0f;
            out[OFF_SCORES + orow] = -1.0f;
            out[OFF_LABELS + orow] = -1.0f;
            sel_anchor[orow] = -1;
        }
    }
}

// ---------------------------------------------------------------------------
// K3: l_classification argmax for each selected row. One wave per row.
// ---------------------------------------------------------------------------
__global__ __launch_bounds__(256) void k3_lcls(const float* __restrict__ lcls,
                                               const int* __restrict__ sel_anchor,
                                               float* __restrict__ out) {
    const int wave = threadIdx.x >> 6, lane = threadIdx.x & 63;
    const int r = blockIdx.x * 4 + wave;
    if (r >= BB * MAX_DET) return;
    const int b = r / MAX_DET;
    const int sel = sel_anchor[r];
    if (sel < 0) {
        if (lane == 0) {
            out[OFF_LSC + r] = -1.0f;
            out[OFF_LLB + r] = -1.0f;
        }
        return;
    }
    const float* row = lcls + ((size_t)b * NN + sel) * LL;
    float bv = -3.402823e38f;
    int bi = 0x7FFFFFFF;
    for (int idx = lane; idx < LL; idx += 64) {
        float v = row[idx];
        if (v > bv) { bv = v; bi = idx; }  // ascending idx + strict > == first max
    }
    for (int off = 32; off > 0; off >>= 1) {
        float ov = __shfl_xor(bv, off);
        int oi = __shfl_xor(bi, off);
        if (ov > bv || (ov == bv && oi < bi)) { bv = ov; bi = oi; }
    }
    if (lane == 0) {
        out[OFF_LSC + r] = bv;
        out[OFF_LLB + r] = (float)bi;
    }
}

// ---------------------------------------------------------------------------
extern "C" void kernel_launch(void* const* d_in, const int* in_sizes, int n_in,
                              void* d_out, int out_size, void* d_ws, size_t ws_size,
                              hipStream_t stream) {
    const float* boxes = (const float*)d_in[0];
    const float* cls = (const float*)d_in[1];
    const float* lcls = (const float*)d_in[2];
    float* out = (float*)d_out;

    // ws layout: cand_score[B*C*300] f32 | cand_anchor[B*C*300] i32 | sel_anchor[B*300] i32
    float* cand_score = (float*)d_ws;
    int* cand_anchor = (int*)(cand_score + BB * CC * MAX_DET);
    int* sel_anchor = cand_anchor + BB * CC * MAX_DET;

    hipLaunchKernelGGL(k1_nms, dim3(BB * CC), dim3(256), 0, stream,
                       boxes, cls, cand_score, cand_anchor);
    hipLaunchKernelGGL(k2_topk, dim3(BB), dim3(256), 0, stream,
                       boxes, cand_score, cand_anchor, out, sel_anchor);
    hipLaunchKernelGGL(k3_lcls, dim3((BB * MAX_DET + 3) / 4), dim3(256), 0, stream,
                       lcls, sel_anchor, out);
}